// Round 1
// baseline (223.383 us; speedup 1.0000x reference)
//
#include <hip/hip_runtime.h>

// ALiBi positional bias, fp32:
//   out[b,h,i,j] = in[b,h,i,j] + slope[h] * ( -|j - i| )
// B=2, H=16, S=2048. H=16 is a power of two:
//   slope[h] = 2^{-0.5*(h+1)}  (exact; matches reference _alibi_slopes)
// Pure streaming op -> float4 vectorized grid-stride loop.

#define S_LOG2 11          // S = 2048
#define ROW4_LOG2 9        // float4s per row = 512
#define H_MASK 15          // H = 16

__global__ __launch_bounds__(256) void alibi_bias_kernel(
    const float* __restrict__ in, float* __restrict__ out, long long n4) {
    long long idx    = (long long)blockIdx.x * blockDim.x + threadIdx.x;
    long long stride = (long long)gridDim.x * blockDim.x;
    const float4* __restrict__ in4  = reinterpret_cast<const float4*>(in);
    float4* __restrict__       out4 = reinterpret_cast<float4*>(out);

    for (long long f = idx; f < n4; f += stride) {
        int  jv  = (int)(f & ((1 << ROW4_LOG2) - 1));   // float4 index within row
        long long row = f >> ROW4_LOG2;                 // global row = ((b*H+h)*S + i)
        int  i   = (int)(row & ((1 << S_LOG2) - 1));
        int  h   = (int)((row >> S_LOG2) & H_MASK);

        float slope = exp2f(-0.5f * (float)(h + 1));

        float4 v = in4[f];
        int j0 = jv << 2;
        v.x -= slope * fabsf((float)(j0 + 0 - i));
        v.y -= slope * fabsf((float)(j0 + 1 - i));
        v.z -= slope * fabsf((float)(j0 + 2 - i));
        v.w -= slope * fabsf((float)(j0 + 3 - i));
        out4[f] = v;
    }
}

extern "C" void kernel_launch(void* const* d_in, const int* in_sizes, int n_in,
                              void* d_out, int out_size, void* d_ws, size_t ws_size,
                              hipStream_t stream) {
    const float* in = (const float*)d_in[0];
    float* out = (float*)d_out;

    long long n  = (long long)out_size;   // 2*16*2048*2048
    long long n4 = n >> 2;                // float4 count

    const int block = 256;
    // Memory-bound: cap grid at ~8 blocks/CU * 256 CUs and grid-stride.
    long long want = (n4 + block - 1) / block;
    int grid = (int)(want < 2048 ? want : 2048);

    alibi_bias_kernel<<<grid, block, 0, stream>>>(in, out, n4);
}

// Round 2
// 222.913 us; speedup vs baseline: 1.0021x; 1.0021x over previous
//
#include <hip/hip_runtime.h>

// ALiBi positional bias, fp32:
//   out[b,h,i,j] = in[b,h,i,j] - slope[h] * |j - i|
// B=2, H=16, S=2048; slope[h] = 2^{-0.5*(h+1)} (H=16 is pow2, exact).
// Streaming memory-bound: float4, unroll x4 for MLP, non-temporal ld/st.

typedef float f32x4 __attribute__((ext_vector_type(4)));

#define ROW4_MASK 511      // float4s per row - 1  (512 per row)
#define S_MASK   2047      // S - 1
#define S_LOG2     11
#define ROW4_LOG2   9

__device__ __forceinline__ f32x4 apply_bias(f32x4 v, long long f) {
    int jv = (int)(f & ROW4_MASK);             // float4 index within row
    long long row = f >> ROW4_LOG2;            // ((b*H + h)*S + i)
    int i = (int)(row & S_MASK);
    int h = (int)((row >> S_LOG2) & 15);
    float slope = exp2f(-0.5f * (float)(h + 1));
    int j0 = jv << 2;
    v.x -= slope * fabsf((float)(j0 + 0 - i));
    v.y -= slope * fabsf((float)(j0 + 1 - i));
    v.z -= slope * fabsf((float)(j0 + 2 - i));
    v.w -= slope * fabsf((float)(j0 + 3 - i));
    return v;
}

__global__ __launch_bounds__(256) void alibi_bias_kernel(
    const float* __restrict__ in, float* __restrict__ out, long long n4) {
    long long idx    = (long long)blockIdx.x * blockDim.x + threadIdx.x;
    long long stride = (long long)gridDim.x * blockDim.x;
    const f32x4* __restrict__ in4  = reinterpret_cast<const f32x4*>(in);
    f32x4* __restrict__       out4 = reinterpret_cast<f32x4*>(out);

    long long f = idx;
    // Batched unroll x4: issue all 4 loads before any compute/store (MLP).
    for (; f + 3 * stride < n4; f += 4 * stride) {
        long long f0 = f, f1 = f + stride, f2 = f + 2 * stride, f3 = f + 3 * stride;
        f32x4 v0 = __builtin_nontemporal_load(&in4[f0]);
        f32x4 v1 = __builtin_nontemporal_load(&in4[f1]);
        f32x4 v2 = __builtin_nontemporal_load(&in4[f2]);
        f32x4 v3 = __builtin_nontemporal_load(&in4[f3]);
        v0 = apply_bias(v0, f0);
        v1 = apply_bias(v1, f1);
        v2 = apply_bias(v2, f2);
        v3 = apply_bias(v3, f3);
        __builtin_nontemporal_store(v0, &out4[f0]);
        __builtin_nontemporal_store(v1, &out4[f1]);
        __builtin_nontemporal_store(v2, &out4[f2]);
        __builtin_nontemporal_store(v3, &out4[f3]);
    }
    for (; f < n4; f += stride) {
        f32x4 v = __builtin_nontemporal_load(&in4[f]);
        v = apply_bias(v, f);
        __builtin_nontemporal_store(v, &out4[f]);
    }
}

extern "C" void kernel_launch(void* const* d_in, const int* in_sizes, int n_in,
                              void* d_out, int out_size, void* d_ws, size_t ws_size,
                              hipStream_t stream) {
    const float* in = (const float*)d_in[0];
    float* out = (float*)d_out;

    long long n  = (long long)out_size;   // 2*16*2048*2048
    long long n4 = n >> 2;                // float4 count

    const int block = 256;
    long long want = (n4 + block - 1) / block;
    int grid = (int)(want < 2048 ? want : 2048);  // 8 blocks/CU -> 32 waves/CU

    alibi_bias_kernel<<<grid, block, 0, stream>>>(in, out, n4);
}

// Round 3
// 202.285 us; speedup vs baseline: 1.1043x; 1.1020x over previous
//
#include <hip/hip_runtime.h>

// ALiBi positional bias, fp32:
//   out[b,h,i,j] = in[b,h,i,j] - slope[h] * |j - i|
// B=2, H=16, S=2048; slope[h] = 2^{-0.5*(h+1)} (H=16 pow2, exact).
//
// R2: block-contiguous layout. Each block owns 16 consecutive rows
// (8192 float4 = 128 KiB contiguous). h / slope / i_base are block-uniform
// (scalar regs, computed once). All inner addressing is 32-bit. Inner loop:
// 8 batches of {4 coalesced 16B loads -> compute -> 4 stores}.

typedef float f32x4 __attribute__((ext_vector_type(4)));

__global__ __launch_bounds__(256) void alibi_bias_kernel(
    const float* __restrict__ in, float* __restrict__ out) {
    // Block-uniform geometry: 16 rows per block, 2048 rows per head.
    const int i_base = (blockIdx.x << 4) & 2047;        // first i this block
    const int h      = (blockIdx.x >> 7) & 15;          // head index
    const float slope = exp2f(-0.5f * (float)(h + 1));  // uniform -> sgpr

    const long long base4 = (long long)blockIdx.x << 13; // 8192 float4s/block
    const f32x4* __restrict__ in4  = reinterpret_cast<const f32x4*>(in)  + base4;
    f32x4* __restrict__       out4 = reinterpret_cast<f32x4*>(out) + base4;

    const int tid = threadIdx.x;

    for (int it = 0; it < 8; ++it) {
        int l0 = (it << 10) + tid;           // + u*256, u=0..3
        int l1 = l0 + 256;
        int l2 = l0 + 512;
        int l3 = l0 + 768;

        f32x4 v0 = __builtin_nontemporal_load(&in4[l0]);
        f32x4 v1 = __builtin_nontemporal_load(&in4[l1]);
        f32x4 v2 = __builtin_nontemporal_load(&in4[l2]);
        f32x4 v3 = __builtin_nontemporal_load(&in4[l3]);

        {
            int i = i_base + (l0 >> 9);
            float d = (float)((l0 & 511) * 4 - i);
            v0.x -= slope * fabsf(d);
            v0.y -= slope * fabsf(d + 1.0f);
            v0.z -= slope * fabsf(d + 2.0f);
            v0.w -= slope * fabsf(d + 3.0f);
        }
        {
            int i = i_base + (l1 >> 9);
            float d = (float)((l1 & 511) * 4 - i);
            v1.x -= slope * fabsf(d);
            v1.y -= slope * fabsf(d + 1.0f);
            v1.z -= slope * fabsf(d + 2.0f);
            v1.w -= slope * fabsf(d + 3.0f);
        }
        {
            int i = i_base + (l2 >> 9);
            float d = (float)((l2 & 511) * 4 - i);
            v2.x -= slope * fabsf(d);
            v2.y -= slope * fabsf(d + 1.0f);
            v2.z -= slope * fabsf(d + 2.0f);
            v2.w -= slope * fabsf(d + 3.0f);
        }
        {
            int i = i_base + (l3 >> 9);
            float d = (float)((l3 & 511) * 4 - i);
            v3.x -= slope * fabsf(d);
            v3.y -= slope * fabsf(d + 1.0f);
            v3.z -= slope * fabsf(d + 2.0f);
            v3.w -= slope * fabsf(d + 3.0f);
        }

        __builtin_nontemporal_store(v0, &out4[l0]);
        __builtin_nontemporal_store(v1, &out4[l1]);
        __builtin_nontemporal_store(v2, &out4[l2]);
        __builtin_nontemporal_store(v3, &out4[l3]);
    }
}

extern "C" void kernel_launch(void* const* d_in, const int* in_sizes, int n_in,
                              void* d_out, int out_size, void* d_ws, size_t ws_size,
                              hipStream_t stream) {
    const float* in = (const float*)d_in[0];
    float* out = (float*)d_out;

    // n = 2*16*2048*2048 = 2^27 elements = 2^25 float4s... (actually 2^27/4 = 2^25)
    // Each block covers 8192 float4s -> grid = 2^25 / 2^13 = 4096 blocks.
    long long n4 = (long long)out_size >> 2;
    int grid = (int)(n4 >> 13);

    alibi_bias_kernel<<<grid, 256, 0, stream>>>(in, out);
}

// Round 4
// 189.872 us; speedup vs baseline: 1.1765x; 1.0654x over previous
//
#include <hip/hip_runtime.h>

// ALiBi positional bias, fp32:
//   out[b,h,i,j] = in[b,h,i,j] - slope[h] * |j - i|
// B=2, H=16, S=2048; slope[h] = 2^{-0.5*(h+1)} (H=16 pow2, exact).
//
// R3: R2's block-contiguous layout (16 rows / 128 KiB per block,
// slope & i_base block-uniform) + software pipeline: prefetch next
// batch's 4 loads BEFORE compute+store of current batch, so the read
// stream never stalls behind store drain. Index math strength-reduced:
// per-lane distance base d = 4*tid - i_base - 2*it (d -= 2 per iter);
// batch offsets are the constants {0, +1024, -1, +1023}.

typedef float f32x4 __attribute__((ext_vector_type(4)));

__device__ __forceinline__ void apply4(f32x4& v, float d, float ns) {
    v.x = fmaf(ns, fabsf(d),        v.x);
    v.y = fmaf(ns, fabsf(d + 1.0f), v.y);
    v.z = fmaf(ns, fabsf(d + 2.0f), v.z);
    v.w = fmaf(ns, fabsf(d + 3.0f), v.w);
}

__global__ __launch_bounds__(256) void alibi_bias_kernel(
    const float* __restrict__ in, float* __restrict__ out) {
    const int i_base = (blockIdx.x << 4) & 2047;        // first row i of block
    const int h      = (blockIdx.x >> 7) & 15;          // head index
    const float nslope = -exp2f(-0.5f * (float)(h + 1));

    const long long base4 = (long long)blockIdx.x << 13; // 8192 float4s/block
    const f32x4* __restrict__ in4  = reinterpret_cast<const f32x4*>(in)  + base4;
    f32x4* __restrict__       out4 = reinterpret_cast<f32x4*>(out) + base4;

    const int tid = threadIdx.x;

    // Prologue: load batch 0.
    f32x4 a0 = __builtin_nontemporal_load(&in4[tid]);
    f32x4 a1 = __builtin_nontemporal_load(&in4[tid + 256]);
    f32x4 a2 = __builtin_nontemporal_load(&in4[tid + 512]);
    f32x4 a3 = __builtin_nontemporal_load(&in4[tid + 768]);

    float d = (float)((tid << 2) - i_base);  // distance base, batch 0

#pragma unroll
    for (int it = 0; it < 8; ++it) {
        f32x4 b0, b1, b2, b3;
        if (it < 7) {
            // Prefetch next batch first — keeps reads in flight while
            // this batch's stores drain.
            int l = ((it + 1) << 10) + tid;
            b0 = __builtin_nontemporal_load(&in4[l]);
            b1 = __builtin_nontemporal_load(&in4[l + 256]);
            b2 = __builtin_nontemporal_load(&in4[l + 512]);
            b3 = __builtin_nontemporal_load(&in4[l + 768]);
        }

        apply4(a0, d,           nslope);   // row 2*it,   cols 4*tid
        apply4(a1, d + 1024.0f, nslope);   // row 2*it,   cols 4*tid+1024
        apply4(a2, d - 1.0f,    nslope);   // row 2*it+1, cols 4*tid
        apply4(a3, d + 1023.0f, nslope);   // row 2*it+1, cols 4*tid+1024

        int s = (it << 10) + tid;
        __builtin_nontemporal_store(a0, &out4[s]);
        __builtin_nontemporal_store(a1, &out4[s + 256]);
        __builtin_nontemporal_store(a2, &out4[s + 512]);
        __builtin_nontemporal_store(a3, &out4[s + 768]);

        a0 = b0; a1 = b1; a2 = b2; a3 = b3;
        d -= 2.0f;
    }
}

extern "C" void kernel_launch(void* const* d_in, const int* in_sizes, int n_in,
                              void* d_out, int out_size, void* d_ws, size_t ws_size,
                              hipStream_t stream) {
    const float* in = (const float*)d_in[0];
    float* out = (float*)d_out;

    long long n4 = (long long)out_size >> 2;   // 2^25 float4s
    int grid = (int)(n4 >> 13);                // 8192 float4s per block -> 4096

    alibi_bias_kernel<<<grid, 256, 0, stream>>>(in, out);
}

// Round 5
// 188.235 us; speedup vs baseline: 1.1867x; 1.0087x over previous
//
#include <hip/hip_runtime.h>

// ALiBi positional bias, fp32:
//   out[b,h,i,j] = in[b,h,i,j] - slope[h] * |j - i|
// B=2, H=16, S=2048; slope[h] = 2^{-0.5*(h+1)} (H=16 pow2, exact).
//
// R4: R3 + prefetch depth 2 (triple-buffered regs, 8 loads in flight).
// Decouples compute's vmcnt wait from the previous iteration's store
// drain (vmcnt counts loads AND stores in order). Block owns 16 rows
// (128 KiB contiguous); slope / i_base block-uniform; distance base
// strength-reduced to d -= 2 per iteration.

typedef float f32x4 __attribute__((ext_vector_type(4)));

__device__ __forceinline__ void apply4(f32x4& v, float d, float ns) {
    v.x = fmaf(ns, fabsf(d),        v.x);
    v.y = fmaf(ns, fabsf(d + 1.0f), v.y);
    v.z = fmaf(ns, fabsf(d + 2.0f), v.z);
    v.w = fmaf(ns, fabsf(d + 3.0f), v.w);
}

__global__ __launch_bounds__(256) void alibi_bias_kernel(
    const float* __restrict__ in, float* __restrict__ out) {
    const int i_base = (blockIdx.x << 4) & 2047;        // first row i of block
    const int h      = (blockIdx.x >> 7) & 15;          // head index
    const float nslope = -exp2f(-0.5f * (float)(h + 1));

    const long long base4 = (long long)blockIdx.x << 13; // 8192 float4s/block
    const f32x4* __restrict__ in4  = reinterpret_cast<const f32x4*>(in)  + base4;
    f32x4* __restrict__       out4 = reinterpret_cast<f32x4*>(out) + base4;

    const int tid = threadIdx.x;

    // Prologue: batches 0 and 1 in flight.
    f32x4 a0 = __builtin_nontemporal_load(&in4[tid]);
    f32x4 a1 = __builtin_nontemporal_load(&in4[tid + 256]);
    f32x4 a2 = __builtin_nontemporal_load(&in4[tid + 512]);
    f32x4 a3 = __builtin_nontemporal_load(&in4[tid + 768]);
    f32x4 b0 = __builtin_nontemporal_load(&in4[tid + 1024]);
    f32x4 b1 = __builtin_nontemporal_load(&in4[tid + 1280]);
    f32x4 b2 = __builtin_nontemporal_load(&in4[tid + 1536]);
    f32x4 b3 = __builtin_nontemporal_load(&in4[tid + 1792]);

    float d = (float)((tid << 2) - i_base);  // distance base, batch 0

#pragma unroll
    for (int it = 0; it < 8; ++it) {
        f32x4 c0, c1, c2, c3;
        if (it < 6) {
            // Prefetch batch it+2: consumed loads get a full extra
            // iteration of slack past the store drain.
            int l = ((it + 2) << 10) + tid;
            c0 = __builtin_nontemporal_load(&in4[l]);
            c1 = __builtin_nontemporal_load(&in4[l + 256]);
            c2 = __builtin_nontemporal_load(&in4[l + 512]);
            c3 = __builtin_nontemporal_load(&in4[l + 768]);
        }

        apply4(a0, d,           nslope);   // row 2*it,   cols 4*tid
        apply4(a1, d + 1024.0f, nslope);   // row 2*it,   cols 4*tid+1024
        apply4(a2, d - 1.0f,    nslope);   // row 2*it+1, cols 4*tid
        apply4(a3, d + 1023.0f, nslope);   // row 2*it+1, cols 4*tid+1024

        int s = (it << 10) + tid;
        __builtin_nontemporal_store(a0, &out4[s]);
        __builtin_nontemporal_store(a1, &out4[s + 256]);
        __builtin_nontemporal_store(a2, &out4[s + 512]);
        __builtin_nontemporal_store(a3, &out4[s + 768]);

        a0 = b0; a1 = b1; a2 = b2; a3 = b3;
        b0 = c0; b1 = c1; b2 = c2; b3 = c3;
        d -= 2.0f;
    }
}

extern "C" void kernel_launch(void* const* d_in, const int* in_sizes, int n_in,
                              void* d_out, int out_size, void* d_ws, size_t ws_size,
                              hipStream_t stream) {
    const float* in = (const float*)d_in[0];
    float* out = (float*)d_out;

    long long n4 = (long long)out_size >> 2;   // 2^25 float4s
    int grid = (int)(n4 >> 13);                // 8192 float4s per block -> 4096

    alibi_bias_kernel<<<grid, 256, 0, stream>>>(in, out);
}